// Round 10
// baseline (565.355 us; speedup 1.0000x reference)
//
#include <hip/hip_runtime.h>
#include <hip/hip_bf16.h>
#include <math.h>

#define TSEQ 2048
#define DIN  32
#define HID  20
#define G4   80
#define TILE 16
#define NT   (TSEQ / TILE)
#define CHUNK 256               // rows per xg block (phase 1)
#define NCHUNK (TSEQ / CHUNK)   // 8
#define L2E  1.44269504088896340736f

#if __has_builtin(__builtin_amdgcn_exp2f)
#define EXP2(x) __builtin_amdgcn_exp2f(x)
#else
#define EXP2(x) __expf((x) * 0.69314718055994531f)
#endif

typedef unsigned int uint2v __attribute__((ext_vector_type(2)));

__device__ __forceinline__ float rl(float v, int l) {
    return __int_as_float(__builtin_amdgcn_readlane(__float_as_int(v), l));
}

__device__ __forceinline__ float sig2(float xs) {   // 1/(1+2^-xs)
    return __builtin_amdgcn_rcpf(1.0f + EXP2(-xs));
}

// cross-half (lane ^ 32) exchange. HAZARD-SAFE version: the gfx950 BUILTIN
// (not inline asm) so the compiler's hazard recognizer inserts the required
// VALU->permlane wait states. Inline-asm permlane was the suspected source
// of the non-deterministic R3/R5/R6/R9 failures.
// Semantics: swap(vdst_hi <-> vsrc_lo); with both inputs = v the two results
// are [v_lo|v_lo] and [v_hi|v_hi], so r.x + r.y - v = opposite-half value.
__device__ __forceinline__ float xhalf(float v) {
#if __has_builtin(__builtin_amdgcn_permlane32_swap)
    uint2v r = __builtin_amdgcn_permlane32_swap(__float_as_uint(v),
                                                __float_as_uint(v),
                                                false, false);
    return (__uint_as_float(r.x) + __uint_as_float(r.y)) - v;
#else
    return __shfl_xor(v, 32);   // DS-based, slower but proven (R1)
#endif
}

__device__ __forceinline__ float samp(const float* mu, const float* rho,
                                      const float* eps, int i) {
    return mu[i] + log1pf(__expf(rho[i])) * eps[i];
}

// ============================ PHASE 1: xg GEMM ============================
__global__ __launch_bounds__(64, 1) void xg_kernel(
    const float* __restrict__ x,
    const float* __restrict__ wih_mu, const float* __restrict__ wih_rho, const float* __restrict__ wih_eps,
    const float* __restrict__ bmu,    const float* __restrict__ brho,    const float* __restrict__ beps,
    float* __restrict__ xg_ws)
{
    const int lane = threadIdx.x;
    const int b    = blockIdx.x / NCHUNK;
    const int ch   = blockIdx.x % NCHUNK;
    const float* xu = x + ((size_t)b * TSEQ + (size_t)ch * CHUNK) * DIN;
    float* xgo = xg_ws + ((size_t)b * TSEQ + (size_t)ch * CHUNK) * G4;

    const int cA = lane;                       // columns 0..63
    const int cB = 64 + (lane & 15);           // columns 64..79 ('o' tail)
    const float scA = ((cA >= 40 && cA < 60) ? 2.0f : 1.0f) * L2E;
    const float scB = L2E;

    float wA[DIN], wB[DIN];
#pragma unroll
    for (int d = 0; d < DIN; ++d) {
        wA[d] = samp(wih_mu, wih_rho, wih_eps, d * G4 + cA) * scA;
        wB[d] = samp(wih_mu, wih_rho, wih_eps, d * G4 + cB) * scB;
    }
    const float biasA = samp(bmu, brho, beps, cA) * scA;
    const float biasB = samp(bmu, brho, beps, cB) * scB;

    const int posA = ((cA >= 40) ? 40 : 0) + (cA % 20) * 2 + ((cA / 20) & 1);
    const int posB = 40 + (cB % 20) * 2 + 1;   // 'o' columns

#pragma unroll 4
    for (int s = 0; s < CHUNK; ++s) {
        const float* xs = xu + s * DIN;        // wave-uniform -> s_loads
        float a0 = 0.f, a1 = 0.f, b0 = 0.f, b1 = 0.f;
#pragma unroll
        for (int d = 0; d < 16; ++d) {
            const float xe = xs[d], xo = xs[d + 16];
            a0 = fmaf(xe, wA[d],      a0);
            a1 = fmaf(xo, wA[d + 16], a1);
            b0 = fmaf(xe, wB[d],      b0);
            b1 = fmaf(xo, wB[d + 16], b1);
        }
        xgo[s * G4 + posA] = biasA + a0 + a1;
        if (lane < 16) xgo[s * G4 + posB] = biasB + b0 + b1;
    }
}

// ========================= PHASE 2: recurrence ===========================
__global__ __launch_bounds__(64, 1) void rec_kernel(
    const float* __restrict__ xg_ws,
    const float* __restrict__ whh_mu, const float* __restrict__ whh_rho, const float* __restrict__ whh_eps,
    const float* __restrict__ wlin,   const float* __restrict__ blin,
    float* __restrict__ out)
{
    __shared__ __align__(16) float hist[64 * HID];

    const int lane = threadIdx.x;
    const int b    = blockIdx.x;
    const int p  = lane >> 5;
    const int k  = lane & 31;
    const int ke = (k < HID) ? k : (HID - 1);
    const int g1 = p * 40 + ke;
    const int g2 = g1 + HID;
    const float aAct = p ? 2.0f : 1.0f;
    const float cAct = 1.0f - aAct;
    const float sc1 = aAct * L2E;
    const float sc2 = L2E;

    float w1[HID], w2[HID];
#pragma unroll
    for (int j = 0; j < HID; ++j) {
        w1[j] = samp(whh_mu, whh_rho, whh_eps, j * G4 + g1) * sc1;
        w2[j] = samp(whh_mu, whh_rho, whh_eps, j * G4 + g2) * sc2;
    }
    const int coff = p * 40 + ke * 2;

    float wl[HID];
#pragma unroll
    for (int j = 0; j < HID; ++j) wl[j] = wlin[j];
    const float bl = blin[0];

    const float* xgb = xg_ws + (size_t)b * TSEQ * G4;
    float* outp = out + (size_t)b * TSEQ;

    float h = 0.0f, c = 0.0f;
    float2 xa[TILE], xb[TILE];

    auto loadt = [&](float2* dst, int kt) {
        const float* rowp = xgb + (size_t)kt * TILE * G4 + coff;
#pragma unroll
        for (int s = 0; s < TILE; ++s)
            dst[s] = *(const float2*)(rowp + s * G4);
    };

    auto steps = [&](const float2* xr, int kt) {
#pragma unroll
        for (int ti = 0; ti < TILE; ++ti) {
            float hj[HID];
#pragma unroll
            for (int j = 0; j < HID; ++j) hj[j] = rl(h, j);

            float d1a = xr[ti].x, d2a = xr[ti].y;
            float d1b = 0.0f, d2b = 0.0f;
#pragma unroll
            for (int j = 0; j < HID; j += 2) {
                d1a = fmaf(hj[j],     w1[j],     d1a);
                d2a = fmaf(hj[j],     w2[j],     d2a);
                d1b = fmaf(hj[j + 1], w1[j + 1], d1b);
                d2b = fmaf(hj[j + 1], w2[j + 1], d2b);
            }
            const float d1 = d1a + d1b;
            const float d2 = d2a + d2b;

            const float s1   = sig2(d1);               // sig(i) or sig(2g)
            const float act1 = fmaf(s1, aAct, cAct);   // sig(i) or tanh(g)
            const float act2 = sig2(d2);               // sig(f) or sig(o)

            const float og1 = xhalf(act1);             // low lanes: tanh(g)
            const float og2 = xhalf(act2);             // low lanes: sig(o)

            c = fmaf(act2, c, act1 * og1);             // low: f*c + i*tanh(g)
            const float tc = fmaf(2.0f, sig2(c * (2.0f * L2E)), -1.0f); // tanh(c)
            h = og2 * tc;                              // low: o * tanh(c)

            const int t = kt * TILE + ti;
            if (lane < HID) hist[(t & 63) * HID + lane] = h;

            if ((t & 63) == 63) {                      // R1-proven inline flush
                const float4* hr = (const float4*)&hist[lane * HID];
                const float4 r0 = hr[0], r1 = hr[1], r2 = hr[2], r3 = hr[3], r4 = hr[4];
                float acc = bl;
                acc = fmaf(r0.x, wl[0],  acc); acc = fmaf(r0.y, wl[1],  acc);
                acc = fmaf(r0.z, wl[2],  acc); acc = fmaf(r0.w, wl[3],  acc);
                acc = fmaf(r1.x, wl[4],  acc); acc = fmaf(r1.y, wl[5],  acc);
                acc = fmaf(r1.z, wl[6],  acc); acc = fmaf(r1.w, wl[7],  acc);
                acc = fmaf(r2.x, wl[8],  acc); acc = fmaf(r2.y, wl[9],  acc);
                acc = fmaf(r2.z, wl[10], acc); acc = fmaf(r2.w, wl[11], acc);
                acc = fmaf(r3.x, wl[12], acc); acc = fmaf(r3.y, wl[13], acc);
                acc = fmaf(r3.z, wl[14], acc); acc = fmaf(r3.w, wl[15], acc);
                acc = fmaf(r4.x, wl[16], acc); acc = fmaf(r4.y, wl[17], acc);
                acc = fmaf(r4.z, wl[18], acc); acc = fmaf(r4.w, wl[19], acc);
                outp[(t - 63) + lane] = acc;
            }
        }
    };

    loadt(xa, 0);
    for (int kt = 0; kt < NT; kt += 2) {
        loadt(xb, kt + 1);                     // prefetch next tile
        steps(xa, kt);
        if (kt + 2 < NT) loadt(xa, kt + 2);    // prefetch next-next
        steps(xb, kt + 1);
    }
}

// ===================== FALLBACK: R7 fused (proven 435us) =====================
__global__ __launch_bounds__(128, 1) void blstm_fused(
    const float* __restrict__ x,
    const float* __restrict__ wih_mu, const float* __restrict__ wih_rho, const float* __restrict__ wih_eps,
    const float* __restrict__ whh_mu, const float* __restrict__ whh_rho, const float* __restrict__ whh_eps,
    const float* __restrict__ bmu,    const float* __restrict__ brho,    const float* __restrict__ beps,
    const float* __restrict__ wlin,   const float* __restrict__ blin,
    float* __restrict__ out)
{
    __shared__ __align__(16) float lds_xg[2][TILE * G4];
    __shared__ __align__(16) float lds_x[TILE * DIN];
    __shared__ __align__(16) float hist[64 * HID];

    const int tid  = threadIdx.x;
    const int lane = tid & 63;
    const int b    = blockIdx.x;
    const float* xrow = x + (size_t)b * TSEQ * DIN;
    float* outp = out + (size_t)b * TSEQ;

    if (tid < 64) {
        const int p  = lane >> 5;
        const int k  = lane & 31;
        const int ke = (k < HID) ? k : (HID - 1);
        const int g1 = p * 40 + ke;
        const int g2 = g1 + HID;
        const float aAct = p ? 2.0f : 1.0f;
        const float cAct = 1.0f - aAct;
        const float sc1 = aAct * L2E;
        const float sc2 = L2E;

        float w1[HID], w2[HID];
#pragma unroll
        for (int j = 0; j < HID; ++j) {
            w1[j] = samp(whh_mu, whh_rho, whh_eps, j * G4 + g1) * sc1;
            w2[j] = samp(whh_mu, whh_rho, whh_eps, j * G4 + g2) * sc2;
        }
        const int coff = p * 40 + ke * 2;

        float h = 0.0f, c = 0.0f;
        for (int kt = 0; kt < NT; ++kt) {
            __syncthreads();
            const float* xg = lds_xg[kt & 1];
            float2 xgr[TILE];
#pragma unroll
            for (int r = 0; r < TILE; ++r)
                xgr[r] = *(const float2*)&xg[r * G4 + coff];

#pragma unroll
            for (int ti = 0; ti < TILE; ++ti) {
                float hj[HID];
#pragma unroll
                for (int j = 0; j < HID; ++j) hj[j] = rl(h, j);

                float d1a = xgr[ti].x, d2a = xgr[ti].y;
                float d1b = 0.0f, d2b = 0.0f;
#pragma unroll
                for (int j = 0; j < HID; j += 2) {
                    d1a = fmaf(hj[j],     w1[j],     d1a);
                    d2a = fmaf(hj[j],     w2[j],     d2a);
                    d1b = fmaf(hj[j + 1], w1[j + 1], d1b);
                    d2b = fmaf(hj[j + 1], w2[j + 1], d2b);
                }
                const float d1 = d1a + d1b;
                const float d2 = d2a + d2b;
                const float s1   = sig2(d1);
                const float act1 = fmaf(s1, aAct, cAct);
                const float act2 = sig2(d2);
                const float og1 = xhalf(act1);
                const float og2 = xhalf(act2);
                c = fmaf(act2, c, act1 * og1);
                const float tc = fmaf(2.0f, sig2(c * (2.0f * L2E)), -1.0f);
                h = og2 * tc;
                const int t = kt * TILE + ti;
                if (lane < HID) hist[(t & 63) * HID + lane] = h;
            }
        }
        __syncthreads();
    } else {
        const int cA = lane;
        const int cB = 64 + (lane & 15);
        const float scA = ((cA >= 40 && cA < 60) ? 2.0f : 1.0f) * L2E;
        const float scB = L2E;

        float wA[DIN], wB[DIN];
#pragma unroll
        for (int d = 0; d < DIN; ++d) {
            wA[d] = samp(wih_mu, wih_rho, wih_eps, d * G4 + cA) * scA;
            wB[d] = samp(wih_mu, wih_rho, wih_eps, d * G4 + cB) * scB;
        }
        const float biasA = samp(bmu, brho, beps, cA) * scA;
        const float biasB = samp(bmu, brho, beps, cB) * scB;
        const int posA = ((cA >= 40) ? 40 : 0) + (cA % 20) * 2 + ((cA / 20) & 1);
        const int posB = ((cB >= 40) ? 40 : 0) + (cB % 20) * 2 + ((cB / 20) & 1);
        const int qs   = (lane >> 4) * 4;

        float wl[HID];
#pragma unroll
        for (int j = 0; j < HID; ++j) wl[j] = wlin[j];
        const float bl = blin[0];

        auto produce = [&](int kt) {
            const float* xu = xrow + kt * TILE * DIN;
            float* xgb = lds_xg[kt & 1];
            {
                const float4* src = (const float4*)xu;
                float4 v0 = src[lane * 2 + 0];
                float4 v1 = src[lane * 2 + 1];
                ((float4*)lds_x)[lane * 2 + 0] = v0;
                ((float4*)lds_x)[lane * 2 + 1] = v1;
            }
#pragma unroll
            for (int s = 0; s < TILE; ++s) {
                float a0 = 0.0f, a1 = 0.0f;
#pragma unroll
                for (int d = 0; d < 16; ++d) {
                    a0 = fmaf(xu[s * DIN + d],      wA[d],      a0);
                    a1 = fmaf(xu[s * DIN + d + 16], wA[d + 16], a1);
                }
                xgb[s * G4 + posA] = biasA + a0 + a1;
            }
#pragma unroll
            for (int jj = 0; jj < 4; ++jj) {
                const int s = qs + jj;
                const float4* xr = (const float4*)&lds_x[s * DIN];
                float a0 = 0.0f, a1 = 0.0f;
#pragma unroll
                for (int q = 0; q < 4; ++q) {
                    const float4 u0 = xr[q], u1 = xr[q + 4];
                    a0 = fmaf(u0.x, wB[q * 4 + 0],      a0);
                    a0 = fmaf(u0.y, wB[q * 4 + 1],      a0);
                    a0 = fmaf(u0.z, wB[q * 4 + 2],      a0);
                    a0 = fmaf(u0.w, wB[q * 4 + 3],      a0);
                    a1 = fmaf(u1.x, wB[16 + q * 4 + 0], a1);
                    a1 = fmaf(u1.y, wB[16 + q * 4 + 1], a1);
                    a1 = fmaf(u1.z, wB[16 + q * 4 + 2], a1);
                    a1 = fmaf(u1.w, wB[16 + q * 4 + 3], a1);
                }
                xgb[s * G4 + posB] = biasB + a0 + a1;
            }
        };

        auto flush = [&](int ft) {
            if (lane < TILE) {
                const int t = ft * TILE + lane;
                const float4* hr = (const float4*)&hist[(t & 63) * HID];
                const float4 r0 = hr[0], r1 = hr[1], r2 = hr[2], r3 = hr[3], r4 = hr[4];
                float acc = bl;
                acc = fmaf(r0.x, wl[0],  acc); acc = fmaf(r0.y, wl[1],  acc);
                acc = fmaf(r0.z, wl[2],  acc); acc = fmaf(r0.w, wl[3],  acc);
                acc = fmaf(r1.x, wl[4],  acc); acc = fmaf(r1.y, wl[5],  acc);
                acc = fmaf(r1.z, wl[6],  acc); acc = fmaf(r1.w, wl[7],  acc);
                acc = fmaf(r2.x, wl[8],  acc); acc = fmaf(r2.y, wl[9],  acc);
                acc = fmaf(r2.z, wl[10], acc); acc = fmaf(r2.w, wl[11], acc);
                acc = fmaf(r3.x, wl[12], acc); acc = fmaf(r3.y, wl[13], acc);
                acc = fmaf(r3.z, wl[14], acc); acc = fmaf(r3.w, wl[15], acc);
                acc = fmaf(r4.x, wl[16], acc); acc = fmaf(r4.y, wl[17], acc);
                acc = fmaf(r4.z, wl[18], acc); acc = fmaf(r4.w, wl[19], acc);
                outp[t] = acc;
            }
        };

        produce(0);
        for (int kt = 0; kt < NT; ++kt) {
            __syncthreads();
            if (kt + 1 < NT) produce(kt + 1);
            if (kt >= 1)     flush(kt - 1);
        }
        __syncthreads();
        flush(NT - 1);
    }
}

extern "C" void kernel_launch(void* const* d_in, const int* in_sizes, int n_in,
                              void* d_out, int out_size, void* d_ws, size_t ws_size,
                              hipStream_t stream) {
    const float* x       = (const float*)d_in[0];
    const float* wih_mu  = (const float*)d_in[1];
    const float* wih_rho = (const float*)d_in[2];
    const float* wih_eps = (const float*)d_in[3];
    const float* whh_mu  = (const float*)d_in[4];
    const float* whh_rho = (const float*)d_in[5];
    const float* whh_eps = (const float*)d_in[6];
    const float* bmu     = (const float*)d_in[7];
    const float* brho    = (const float*)d_in[8];
    const float* beps    = (const float*)d_in[9];
    const float* wlin    = (const float*)d_in[10];
    const float* blin    = (const float*)d_in[11];
    float* out = (float*)d_out;

    const int B = in_sizes[0] / (TSEQ * DIN);   // 256
    const size_t need = (size_t)B * TSEQ * G4 * sizeof(float);  // ~168 MB

    if (ws_size >= need) {
        xg_kernel<<<B * NCHUNK, 64, 0, stream>>>(x, wih_mu, wih_rho, wih_eps,
                                                 bmu, brho, beps, (float*)d_ws);
        rec_kernel<<<B, 64, 0, stream>>>((const float*)d_ws,
                                         whh_mu, whh_rho, whh_eps,
                                         wlin, blin, out);
    } else {
        blstm_fused<<<B, 128, 0, stream>>>(x, wih_mu, wih_rho, wih_eps,
                                           whh_mu, whh_rho, whh_eps,
                                           bmu, brho, beps, wlin, blin, out);
    }
}